// Round 1
// baseline (256.249 us; speedup 1.0000x reference)
//
#include <hip/hip_runtime.h>
#include <math.h>

#define NG 1024      // gaussians
#define HH 128
#define WW 128
#define NV 2         // views
#define RB 128       // render block size (threads = pixels per block)
#define SH_C0 0.28209479177387814f
#define SH_C1 0.4886025119029199f

// ---------------- Kernel 1: per-view preprocess + bitonic depth sort ----------------
// grid = NV blocks, block = NG threads. Writes sorted SoA gaussian data to ws:
// ws[(view*9 + field)*NG + i], fields: 0=u 1=v 2=ca 3=cb 4=cc 5=op 6=r 7=g 8=b
__global__ __launch_bounds__(NG) void preprocess_sort_kernel(
    const float* __restrict__ xyz, const float* __restrict__ feats,
    const float* __restrict__ scaling, const float* __restrict__ rotation,
    const float* __restrict__ opacity, const float* __restrict__ C2W,
    const float* __restrict__ intr, float* __restrict__ ws)
{
    __shared__ float s_u[NG], s_v[NG], s_ca[NG], s_cb[NG], s_cc[NG], s_op[NG];
    __shared__ float s_r[NG], s_g[NG], s_b[NG];
    __shared__ float s_key[NG];
    __shared__ int   s_idx[NG];

    const int iv = blockIdx.x;
    const int i  = threadIdx.x;

    const float* c2w = C2W + iv * 16;   // row-major 4x4
    const float fx = intr[iv*4+0], fy = intr[iv*4+1];
    const float cx = intr[iv*4+2], cy = intr[iv*4+3];

    // rigid inverse: Rcw = R^T, tcw = -R^T t
    float Rcw[3][3], tcw[3];
    #pragma unroll
    for (int r = 0; r < 3; ++r)
        #pragma unroll
        for (int c = 0; c < 3; ++c)
            Rcw[r][c] = c2w[c*4 + r];
    #pragma unroll
    for (int r = 0; r < 3; ++r)
        tcw[r] = -(Rcw[r][0]*c2w[3] + Rcw[r][1]*c2w[7] + Rcw[r][2]*c2w[11]);
    const float camx = c2w[3], camy = c2w[7], camz = c2w[11];

    // ---- per-gaussian preprocess ----
    {
        const float X = xyz[i*3+0], Y = xyz[i*3+1], Z = xyz[i*3+2];

        // quaternion -> rotation
        float qw = rotation[i*4+0], qx = rotation[i*4+1];
        float qy = rotation[i*4+2], qz = rotation[i*4+3];
        const float qn = rsqrtf(qw*qw + qx*qx + qy*qy + qz*qz);
        qw *= qn; qx *= qn; qy *= qn; qz *= qn;
        const float R00 = 1.f - 2.f*(qy*qy + qz*qz);
        const float R01 = 2.f*(qx*qy - qw*qz);
        const float R02 = 2.f*(qx*qz + qw*qy);
        const float R10 = 2.f*(qx*qy + qw*qz);
        const float R11 = 1.f - 2.f*(qx*qx + qz*qz);
        const float R12 = 2.f*(qy*qz - qw*qx);
        const float R20 = 2.f*(qx*qz - qw*qy);
        const float R21 = 2.f*(qy*qz + qw*qx);
        const float R22 = 1.f - 2.f*(qx*qx + qy*qy);

        const float s0 = scaling[i*3+0], s1 = scaling[i*3+1], s2 = scaling[i*3+2];
        const float M00 = R00*s0, M01 = R01*s1, M02 = R02*s2;
        const float M10 = R10*s0, M11 = R11*s1, M12 = R12*s2;
        const float M20 = R20*s0, M21 = R21*s1, M22 = R22*s2;

        // cov3d = M M^T (symmetric)
        const float S00 = M00*M00 + M01*M01 + M02*M02;
        const float S01 = M00*M10 + M01*M11 + M02*M12;
        const float S02 = M00*M20 + M01*M21 + M02*M22;
        const float S11 = M10*M10 + M11*M11 + M12*M12;
        const float S12 = M10*M20 + M11*M21 + M12*M22;
        const float S22 = M20*M20 + M21*M21 + M22*M22;

        // cov_cam = Rcw * S * Rcw^T
        float tmp[3][3];
        const float S[3][3] = {{S00,S01,S02},{S01,S11,S12},{S02,S12,S22}};
        #pragma unroll
        for (int r = 0; r < 3; ++r)
            #pragma unroll
            for (int c = 0; c < 3; ++c)
                tmp[r][c] = Rcw[r][0]*S[0][c] + Rcw[r][1]*S[1][c] + Rcw[r][2]*S[2][c];
        float C[3][3];
        #pragma unroll
        for (int r = 0; r < 3; ++r)
            #pragma unroll
            for (int c = 0; c < 3; ++c)
                C[r][c] = tmp[r][0]*Rcw[c][0] + tmp[r][1]*Rcw[c][1] + tmp[r][2]*Rcw[c][2];

        // camera-space position
        const float px_ = Rcw[0][0]*X + Rcw[0][1]*Y + Rcw[0][2]*Z + tcw[0];
        const float py_ = Rcw[1][0]*X + Rcw[1][1]*Y + Rcw[1][2]*Z + tcw[1];
        const float pz_ = Rcw[2][0]*X + Rcw[2][1]*Y + Rcw[2][2]*Z + tcw[2];

        const bool valid = pz_ > 0.2f;
        const float zs = fmaxf(pz_, 0.2f);
        const float izs = 1.f / zs;

        const float u = fx*px_*izs + cx;
        const float v = fy*py_*izs + cy;

        // J rows: (a00, 0, a02), (0, a11, a12)
        const float a00 = fx*izs;
        const float a02 = -fx*px_*izs*izs;
        const float a11 = fy*izs;
        const float a12 = -fy*py_*izs*izs;

        const float c00 = a00*a00*C[0][0] + 2.f*a00*a02*C[0][2] + a02*a02*C[2][2] + 0.3f;
        const float c01 = a00*a11*C[0][1] + a00*a12*C[0][2] + a02*a11*C[1][2] + a02*a12*C[2][2];
        const float c11 = a11*a11*C[1][1] + 2.f*a11*a12*C[1][2] + a12*a12*C[2][2] + 0.3f;

        const float det = fmaxf(c00*c11 - c01*c01, 1e-6f);
        const float idet = 1.f / det;

        // SH color (degree 1)
        float dx = X - camx, dy = Y - camy, dz = Z - camz;
        const float dn = rsqrtf(dx*dx + dy*dy + dz*dz);
        dx *= dn; dy *= dn; dz *= dn;
        const float* f = feats + i*12;   // [4][3]
        float col[3];
        #pragma unroll
        for (int c = 0; c < 3; ++c) {
            float cc_ = SH_C0*f[0*3+c] - SH_C1*dy*f[1*3+c] + SH_C1*dz*f[2*3+c]
                        - SH_C1*dx*f[3*3+c] + 0.5f;
            col[c] = fmaxf(cc_, 0.f);
        }

        s_u[i]  = u;
        s_v[i]  = v;
        s_ca[i] = c11*idet;
        s_cb[i] = -c01*idet;
        s_cc[i] = c00*idet;
        s_op[i] = valid ? opacity[i] : 0.f;
        s_r[i]  = col[0];
        s_g[i]  = col[1];
        s_b[i]  = col[2];
        s_key[i] = valid ? pz_ : INFINITY;
        s_idx[i] = i;
    }

    // ---- bitonic sort ascending by key ----
    for (int k = 2; k <= NG; k <<= 1) {
        for (int j = k >> 1; j > 0; j >>= 1) {
            __syncthreads();
            const int ixj = i ^ j;
            if (ixj > i) {
                const bool up = ((i & k) == 0);
                const float ki = s_key[i], kj = s_key[ixj];
                if ((ki > kj) == up) {
                    s_key[i] = kj; s_key[ixj] = ki;
                    const int ti = s_idx[i];
                    s_idx[i] = s_idx[ixj]; s_idx[ixj] = ti;
                }
            }
        }
    }
    __syncthreads();

    // ---- gather sorted to workspace (SoA) ----
    const int si = s_idx[i];
    float* wv = ws + iv * 9 * NG;
    wv[0*NG + i] = s_u[si];
    wv[1*NG + i] = s_v[si];
    wv[2*NG + i] = s_ca[si];
    wv[3*NG + i] = s_cb[si];
    wv[4*NG + i] = s_cc[si];
    wv[5*NG + i] = s_op[si];
    wv[6*NG + i] = s_r[si];
    wv[7*NG + i] = s_g[si];
    wv[8*NG + i] = s_b[si];
}

// ---------------- Kernel 2: per-pixel front-to-back compositing ----------------
// grid = NV * (HH*WW/RB) blocks, block = RB threads (1 pixel/thread).
__global__ __launch_bounds__(RB) void render_kernel(
    const float* __restrict__ ws, float* __restrict__ out)
{
    __shared__ float l_u[RB], l_v[RB], l_ca[RB], l_cb[RB], l_cc[RB];
    __shared__ float l_op[RB], l_r[RB], l_g[RB], l_b[RB];

    const int bpv = (HH*WW) / RB;
    const int iv  = blockIdx.x / bpv;
    const int pix = (blockIdx.x % bpv) * RB + threadIdx.x;
    const int py  = pix / WW;
    const int px  = pix % WW;
    const float gx = px + 0.5f;
    const float gy = py + 0.5f;

    const float* wv = ws + iv * 9 * NG;

    float T = 1.f, accr = 0.f, accg = 0.f, accb = 0.f;

    for (int c0 = 0; c0 < NG; c0 += RB) {
        const int t = threadIdx.x;
        l_u[t]  = wv[0*NG + c0 + t];
        l_v[t]  = wv[1*NG + c0 + t];
        l_ca[t] = wv[2*NG + c0 + t];
        l_cb[t] = wv[3*NG + c0 + t];
        l_cc[t] = wv[4*NG + c0 + t];
        l_op[t] = wv[5*NG + c0 + t];
        l_r[t]  = wv[6*NG + c0 + t];
        l_g[t]  = wv[7*NG + c0 + t];
        l_b[t]  = wv[8*NG + c0 + t];
        __syncthreads();

        if (T >= 1e-5f) {
            #pragma unroll 4
            for (int j = 0; j < RB; ++j) {
                const float du = gx - l_u[j];
                const float dv = gy - l_v[j];
                const float pw = -0.5f*(l_ca[j]*du*du + l_cc[j]*dv*dv) - l_cb[j]*du*dv;
                if (pw > 0.f) continue;
                float al = fminf(0.99f, l_op[j] * __expf(pw));
                if (al < (1.f/255.f)) continue;
                const float w = al * T;
                accr += w * l_r[j];
                accg += w * l_g[j];
                accb += w * l_b[j];
                T *= (1.f - al);
                if (T < 1e-5f) break;
            }
        }

        // barrier doubles as LDS-reuse protection for next chunk's loads
        if (__syncthreads_and(T < 1e-5f)) break;
    }

    out[((iv*3 + 0)*HH + py)*WW + px] = accr;
    out[((iv*3 + 1)*HH + py)*WW + px] = accg;
    out[((iv*3 + 2)*HH + py)*WW + px] = accb;
}

extern "C" void kernel_launch(void* const* d_in, const int* in_sizes, int n_in,
                              void* d_out, int out_size, void* d_ws, size_t ws_size,
                              hipStream_t stream) {
    const float* xyz      = (const float*)d_in[0];
    const float* feats    = (const float*)d_in[1];
    const float* scaling  = (const float*)d_in[2];
    const float* rotation = (const float*)d_in[3];
    const float* opacity  = (const float*)d_in[4];
    // d_in[5] = height, d_in[6] = width (device scalars; sizes fixed: 128x128)
    const float* C2W      = (const float*)d_in[7];
    const float* intr     = (const float*)d_in[8];

    float* ws  = (float*)d_ws;    // needs NV*9*NG floats = 72 KiB
    float* out = (float*)d_out;

    preprocess_sort_kernel<<<NV, NG, 0, stream>>>(
        xyz, feats, scaling, rotation, opacity, C2W, intr, ws);

    render_kernel<<<NV * (HH*WW / RB), RB, 0, stream>>>(ws, out);
}

// Round 3
// 120.431 us; speedup vs baseline: 2.1278x; 2.1278x over previous
//
#include <hip/hip_runtime.h>
#include <math.h>

#define NG 1024      // gaussians per view
#define HH 128
#define WW 128
#define NV 2         // views
#define SH_C0 0.28209479177387814f
#define SH_C1 0.4886025119029199f

#define RECF 12                     // floats per gaussian record (3x float4)
#define REC_UN   0                  // unsorted records (float offset)
#define REC_SORT (NV*NG*RECF)       // sorted records  (float offset)
#define KEY_OFF  (2*NV*NG*RECF)     // depth keys as uint64[] (float offset; 8B aligned)

#define PIX 16                      // pixels per render block
#define CH  16                      // depth chunks per pixel
#define GPC (NG/CH)                 // gaussians per chunk = 64

// ---------------- Kernel 1: per-gaussian preprocess (no sort) ----------------
// grid = NV blocks, block = NG threads.
// record: [u,v,ca,cb | cc,pwmin,op,r | g,b,0,0]
__global__ __launch_bounds__(NG) void preprocess_kernel(
    const float* __restrict__ xyz, const float* __restrict__ feats,
    const float* __restrict__ scaling, const float* __restrict__ rotation,
    const float* __restrict__ opacity, const float* __restrict__ C2W,
    const float* __restrict__ intr, float* __restrict__ ws)
{
    const int iv = blockIdx.x;
    const int i  = threadIdx.x;

    const float* c2w = C2W + iv * 16;   // row-major 4x4
    const float fx = intr[iv*4+0], fy = intr[iv*4+1];
    const float cx = intr[iv*4+2], cy = intr[iv*4+3];

    // rigid inverse: Rcw = R^T, tcw = -R^T t
    float Rcw[3][3], tcw[3];
    #pragma unroll
    for (int r = 0; r < 3; ++r)
        #pragma unroll
        for (int c = 0; c < 3; ++c)
            Rcw[r][c] = c2w[c*4 + r];
    #pragma unroll
    for (int r = 0; r < 3; ++r)
        tcw[r] = -(Rcw[r][0]*c2w[3] + Rcw[r][1]*c2w[7] + Rcw[r][2]*c2w[11]);
    const float camx = c2w[3], camy = c2w[7], camz = c2w[11];

    const float X = xyz[i*3+0], Y = xyz[i*3+1], Z = xyz[i*3+2];

    // quaternion -> rotation
    float qw = rotation[i*4+0], qx = rotation[i*4+1];
    float qy = rotation[i*4+2], qz = rotation[i*4+3];
    const float qn = rsqrtf(qw*qw + qx*qx + qy*qy + qz*qz);
    qw *= qn; qx *= qn; qy *= qn; qz *= qn;
    const float R00 = 1.f - 2.f*(qy*qy + qz*qz);
    const float R01 = 2.f*(qx*qy - qw*qz);
    const float R02 = 2.f*(qx*qz + qw*qy);
    const float R10 = 2.f*(qx*qy + qw*qz);
    const float R11 = 1.f - 2.f*(qx*qx + qz*qz);
    const float R12 = 2.f*(qy*qz - qw*qx);
    const float R20 = 2.f*(qx*qz - qw*qy);
    const float R21 = 2.f*(qy*qz + qw*qx);
    const float R22 = 1.f - 2.f*(qx*qx + qy*qy);

    const float s0 = scaling[i*3+0], s1 = scaling[i*3+1], s2 = scaling[i*3+2];
    const float M00 = R00*s0, M01 = R01*s1, M02 = R02*s2;
    const float M10 = R10*s0, M11 = R11*s1, M12 = R12*s2;
    const float M20 = R20*s0, M21 = R21*s1, M22 = R22*s2;

    // cov3d = M M^T (symmetric)
    const float S00 = M00*M00 + M01*M01 + M02*M02;
    const float S01 = M00*M10 + M01*M11 + M02*M12;
    const float S02 = M00*M20 + M01*M21 + M02*M22;
    const float S11 = M10*M10 + M11*M11 + M12*M12;
    const float S12 = M10*M20 + M11*M21 + M12*M22;
    const float S22 = M20*M20 + M21*M21 + M22*M22;

    // cov_cam = Rcw * S * Rcw^T
    float tmp[3][3];
    const float S[3][3] = {{S00,S01,S02},{S01,S11,S12},{S02,S12,S22}};
    #pragma unroll
    for (int r = 0; r < 3; ++r)
        #pragma unroll
        for (int c = 0; c < 3; ++c)
            tmp[r][c] = Rcw[r][0]*S[0][c] + Rcw[r][1]*S[1][c] + Rcw[r][2]*S[2][c];
    float C[3][3];
    #pragma unroll
    for (int r = 0; r < 3; ++r)
        #pragma unroll
        for (int c = 0; c < 3; ++c)
            C[r][c] = tmp[r][0]*Rcw[c][0] + tmp[r][1]*Rcw[c][1] + tmp[r][2]*Rcw[c][2];

    // camera-space position
    const float px_ = Rcw[0][0]*X + Rcw[0][1]*Y + Rcw[0][2]*Z + tcw[0];
    const float py_ = Rcw[1][0]*X + Rcw[1][1]*Y + Rcw[1][2]*Z + tcw[1];
    const float pz_ = Rcw[2][0]*X + Rcw[2][1]*Y + Rcw[2][2]*Z + tcw[2];

    const bool valid = pz_ > 0.2f;
    const float zs = fmaxf(pz_, 0.2f);
    const float izs = 1.f / zs;

    const float u = fx*px_*izs + cx;
    const float v = fy*py_*izs + cy;

    // J rows: (a00, 0, a02), (0, a11, a12)
    const float a00 = fx*izs;
    const float a02 = -fx*px_*izs*izs;
    const float a11 = fy*izs;
    const float a12 = -fy*py_*izs*izs;

    const float c00 = a00*a00*C[0][0] + 2.f*a00*a02*C[0][2] + a02*a02*C[2][2] + 0.3f;
    const float c01 = a00*a11*C[0][1] + a00*a12*C[0][2] + a02*a11*C[1][2] + a02*a12*C[2][2];
    const float c11 = a11*a11*C[1][1] + 2.f*a11*a12*C[1][2] + a12*a12*C[2][2] + 0.3f;

    const float det = fmaxf(c00*c11 - c01*c01, 1e-6f);
    const float idet = 1.f / det;

    // SH color (degree 1)
    float dx = X - camx, dy = Y - camy, dz = Z - camz;
    const float dn = rsqrtf(dx*dx + dy*dy + dz*dz);
    dx *= dn; dy *= dn; dz *= dn;
    const float* f = feats + i*12;   // [4][3]
    float col[3];
    #pragma unroll
    for (int c = 0; c < 3; ++c) {
        float cc_ = SH_C0*f[0*3+c] - SH_C1*dy*f[1*3+c] + SH_C1*dz*f[2*3+c]
                    - SH_C1*dx*f[3*3+c] + 0.5f;
        col[c] = fmaxf(cc_, 0.f);
    }

    const float op = valid ? opacity[i] : 0.f;
    const float pwmin = -logf(255.f * op);   // op=0 -> +inf -> gaussian always skipped

    float* rec = ws + REC_UN + (size_t)(iv*NG + i)*RECF;
    rec[0]  = u;        rec[1]  = v;        rec[2]  = c11*idet;  rec[3]  = -c01*idet;
    rec[4]  = c00*idet; rec[5]  = pwmin;    rec[6]  = op;        rec[7]  = col[0];
    rec[8]  = col[1];   rec[9]  = col[2];   rec[10] = 0.f;       rec[11] = 0.f;

    // Exact lexicographic (z, index) key via IEEE bit-pattern monotonicity.
    // All key z values are positive (valid => z > 0.2; invalid => 1e5), so the
    // uint32 bit pattern is strictly monotone in z. Low 10 bits carry the index
    // for stable tie-break, matching jnp.argsort's stability.
    unsigned long long* keys = (unsigned long long*)(ws + KEY_OFF);
    const float zk = valid ? pz_ : 100000.0f;
    keys[iv*NG + i] = (((unsigned long long)__float_as_uint(zk)) << 10)
                    | (unsigned long long)(unsigned)i;
}

// ---------------- Kernel 2: rank computation + sorted scatter ----------------
// grid = NV*8 blocks, block = 256 threads (2 threads per gaussian, 512 keys each)
__global__ __launch_bounds__(256) void rank_scatter_kernel(float* __restrict__ ws)
{
    __shared__ int s_cnt[256];
    const int iv  = blockIdx.x >> 3;
    const int seg = blockIdx.x & 7;
    const int t   = threadIdx.x;
    const int g    = seg*128 + (t & 127);
    const int half = t >> 7;

    const unsigned long long* keys =
        ((const unsigned long long*)(ws + KEY_OFF)) + iv*NG;
    const unsigned long long ki = keys[g];
    const unsigned long long* kp = keys + half*512;
    int cnt = 0;
    #pragma unroll 8
    for (int j = 0; j < 512; ++j)
        cnt += (kp[j] < ki) ? 1 : 0;
    s_cnt[t] = cnt;
    __syncthreads();

    if (t < 128) {
        const int gg   = seg*128 + t;
        const int rank = s_cnt[t] + s_cnt[t+128];
        const float4* src = (const float4*)(ws + REC_UN   + (size_t)(iv*NG + gg)*RECF);
        float4*       dst = (float4*)      (ws + REC_SORT + (size_t)(iv*NG + rank)*RECF);
        dst[0] = src[0]; dst[1] = src[1]; dst[2] = src[2];
    }
}

// ---------------- Kernel 3: chunk-parallel front-to-back compositing ----------------
// block = 256 threads = PIX pixels x CH chunks; grid = NV * (HH*WW/PIX)
__global__ __launch_bounds__(256) void render_kernel(
    const float* __restrict__ ws, float* __restrict__ out)
{
    __shared__ float s_r[CH][PIX], s_g[CH][PIX], s_b[CH][PIX], s_T[CH][PIX];

    const int bpv   = (HH*WW) / PIX;            // 1024 blocks per view
    const int iv    = blockIdx.x / bpv;
    const int pbase = (blockIdx.x % bpv) * PIX;
    const int pl    = threadIdx.x & (PIX-1);
    const int ch    = threadIdx.x >> 4;
    const int pix   = pbase + pl;
    const float gx  = (pix % WW) + 0.5f;
    const float gy  = (pix / WW) + 0.5f;

    // this thread's depth chunk of sorted records
    const float4* gp = (const float4*)(ws + REC_SORT + (size_t)(iv*NG + ch*GPC)*RECF);

    float T = 1.f, ar = 0.f, ag = 0.f, ab = 0.f;

    #pragma unroll 4
    for (int j = 0; j < GPC; ++j) {
        const float4 g0 = gp[j*3+0];            // u,v,ca,cb
        const float4 g1 = gp[j*3+1];            // cc,pwmin,op,r
        const float du = gx - g0.x;
        const float dv = gy - g0.y;
        const float pw = -0.5f*(g0.z*du*du + g1.x*dv*dv) - g0.w*du*dv;
        if (pw <= 0.f && pw >= g1.y) {          // passes alpha >= 1/255 pre-test
            float al = fminf(0.99f, g1.z * __expf(pw));
            if (al >= (1.f/255.f)) {
                const float4 g2 = gp[j*3+2];    // g,b,-,-
                const float w = al * T;
                ar += w * g1.w;
                ag += w * g2.x;
                ab += w * g2.y;
                T *= (1.f - al);
                if (T < 1e-5f) break;           // local chunk transmittance saturated
            }
        }
    }

    s_r[ch][pl] = ar; s_g[ch][pl] = ag; s_b[ch][pl] = ab; s_T[ch][pl] = T;
    __syncthreads();

    // serial prefix-combine over the 16 chunks (associative compositing)
    if (threadIdx.x < PIX) {
        const int p = threadIdx.x;
        float Tg = 1.f, r = 0.f, g = 0.f, b = 0.f;
        #pragma unroll
        for (int c = 0; c < CH; ++c) {
            r += Tg * s_r[c][p];
            g += Tg * s_g[c][p];
            b += Tg * s_b[c][p];
            Tg *= s_T[c][p];
        }
        const int pix2 = pbase + p;
        const int py2 = pix2 / WW, px2 = pix2 % WW;
        out[((iv*3 + 0)*HH + py2)*WW + px2] = r;
        out[((iv*3 + 1)*HH + py2)*WW + px2] = g;
        out[((iv*3 + 2)*HH + py2)*WW + px2] = b;
    }
}

extern "C" void kernel_launch(void* const* d_in, const int* in_sizes, int n_in,
                              void* d_out, int out_size, void* d_ws, size_t ws_size,
                              hipStream_t stream) {
    const float* xyz      = (const float*)d_in[0];
    const float* feats    = (const float*)d_in[1];
    const float* scaling  = (const float*)d_in[2];
    const float* rotation = (const float*)d_in[3];
    const float* opacity  = (const float*)d_in[4];
    // d_in[5] = height, d_in[6] = width (fixed 128x128)
    const float* C2W      = (const float*)d_in[7];
    const float* intr     = (const float*)d_in[8];

    float* ws  = (float*)d_ws;    // needs (2*NV*NG*12)*4 + NV*NG*8 = ~208 KiB
    float* out = (float*)d_out;

    preprocess_kernel<<<NV, NG, 0, stream>>>(
        xyz, feats, scaling, rotation, opacity, C2W, intr, ws);

    rank_scatter_kernel<<<NV*8, 256, 0, stream>>>(ws);

    render_kernel<<<NV * (HH*WW / PIX), 256, 0, stream>>>(ws, out);
}